// Round 8
// baseline (209.042 us; speedup 1.0000x reference)
//
#include <hip/hip_runtime.h>
#include <hip/hip_bf16.h>

namespace {
constexpr int S  = 4096;
constexpr int D  = 768;
constexpr int H  = 12;
constexpr int N3 = 2304;   // 3*D

typedef __bf16 bf16x4 __attribute__((ext_vector_type(4)));
typedef __bf16 bf16x8 __attribute__((ext_vector_type(8)));
typedef float  floatx4 __attribute__((ext_vector_type(4)));

// async global->LDS, 16B per lane; LDS dest = wave-uniform base + lane*16.
__device__ inline void glds16(const __bf16* g, __bf16* l) {
  __builtin_amdgcn_global_load_lds(
      (const __attribute__((address_space(1))) void*)(const void*)g,
      (__attribute__((address_space(3))) void*)(void*)l, 16, 0, 0);
}

// ---------------------------------------------------------------------------
// Kernel 0: merged converts. bid < 3072: x fp32 -> bf16 (1024 elems/block).
// Else: W [768][2304] fp32 -> WT [2304][768] bf16 via LDS tile transpose.
// ---------------------------------------------------------------------------
__global__ __launch_bounds__(256)
void convert_all(const float* __restrict__ x, __bf16* __restrict__ xb,
                 const float* __restrict__ W, __bf16* __restrict__ WT)
{
  const int bid = blockIdx.x;
  const int tid = threadIdx.x;
  if (bid < 3072) {
    const int i = (bid * 256 + tid) * 4;
    floatx4 v = *reinterpret_cast<const floatx4*>(x + i);
    bf16x4 b;
    #pragma unroll
    for (int e = 0; e < 4; ++e) b[e] = (__bf16)v[e];
    *reinterpret_cast<bf16x4*>(xb + i) = b;
  } else {
    __shared__ float T[64][65];
    const int b2 = bid - 3072;
    const int d0 = (b2 % 12) * 64, e0 = (b2 / 12) * 64;
    const int rr = tid >> 4, c4 = (tid & 15) * 4;
    #pragma unroll
    for (int it = 0; it < 4; ++it) {
      int d = it * 16 + rr;
      floatx4 v = *reinterpret_cast<const floatx4*>(W + (d0 + d) * N3 + e0 + c4);
      #pragma unroll
      for (int e = 0; e < 4; ++e) T[d][c4 + e] = v[e];
    }
    __syncthreads();
    #pragma unroll
    for (int it = 0; it < 4; ++it) {
      int e = it * 16 + rr;
      bf16x4 b;
      #pragma unroll
      for (int i = 0; i < 4; ++i) b[i] = (__bf16)T[c4 + i][e];
      *reinterpret_cast<bf16x4*>(WT + (e0 + e) * D + d0 + c4) = b;
    }
  }
}

// ---------------------------------------------------------------------------
// Kernel 1: QKV GEMM — R7 VERBATIM (BK=32 in-place dbuf, 1 barrier/step).
// This round it is dispatched 3x (idempotent) as a timing probe: the total's
// delta over R7 = 2x the gemm dispatch duration, which rocprof's top-5
// cannot show (attention's ~100 dispatches at 84us monopolize the list).
// ---------------------------------------------------------------------------
__global__ __launch_bounds__(256)
void qkv_gemm(const __bf16* __restrict__ xb, const __bf16* __restrict__ WT,
              const float* __restrict__ bq, __bf16* __restrict__ Qb,
              __bf16* __restrict__ Kb, __bf16* __restrict__ vT)
{
  __shared__ __bf16 smem[14336];  // A0[4096] A1[4096] B0[3072] B1[3072]; vts
  const int tid  = threadIdx.x;
  const int wave = tid >> 6, lane = tid & 63;
  const int quad = lane >> 4, l16 = lane & 15;
  const int m_base = (wave >> 1) * 64;
  const int n_base = (wave & 1) * 48;
  const int bm = blockIdx.x, bn = blockIdx.y;

  floatx4 acc[4][3];
  #pragma unroll
  for (int i = 0; i < 4; ++i)
    #pragma unroll
    for (int j = 0; j < 3; ++j) acc[i][j] = (floatx4){0.f, 0.f, 0.f, 0.f};

  // stage one BK=32 half-tile pair into half h
  auto stageA = [&](int k, int h) {
    #pragma unroll
    for (int it = 0; it < 2; ++it) {
      int r0 = it * 64 + wave * 16;
      int row = r0 + (lane >> 2);
      glds16(xb + (size_t)(bm * 128 + row) * D + k * 32
                + (((lane & 3) ^ ((row >> 1) & 3)) * 8),
             smem + h * 4096 + r0 * 32);
    }
  };
  auto stageB = [&](int k, int h) {
    #pragma unroll
    for (int it = 0; it < 2; ++it) {
      int r0 = it * 64 + wave * 16;
      if (r0 < 96) {
        int row = r0 + (lane >> 2);
        glds16(WT + (size_t)(bn * 96 + row) * D + k * 32
                  + (((lane & 3) ^ ((row >> 1) & 3)) * 8),
               smem + 8192 + h * 3072 + r0 * 32);
      }
    }
  };

  __builtin_amdgcn_sched_barrier(0);
  stageA(0, 0); stageB(0, 0);            // prologue
  __builtin_amdgcn_sched_barrier(0);

  for (int k = 0; k < 24; ++k) {
    const int h = k & 1;
    asm volatile("s_waitcnt vmcnt(0)" ::: "memory");   // stage(k) landed
    __builtin_amdgcn_s_barrier();                      // publish k / retire k-1
    __builtin_amdgcn_sched_barrier(0);

    if (k < 23) { stageA(k + 1, h ^ 1); stageB(k + 1, h ^ 1); }
    __builtin_amdgcn_sched_barrier(0);

    bf16x8 af[4], bfr[3];
    #pragma unroll
    for (int mt = 0; mt < 4; ++mt) {
      int m = m_base + mt * 16 + l16;
      af[mt] = *reinterpret_cast<const bf16x8*>(
          &smem[h * 4096 + m * 32 + ((quad ^ ((m >> 1) & 3)) << 3)]);
    }
    #pragma unroll
    for (int nt = 0; nt < 3; ++nt) {
      int n = n_base + nt * 16 + l16;
      bfr[nt] = *reinterpret_cast<const bf16x8*>(
          &smem[8192 + h * 3072 + n * 32 + ((quad ^ ((n >> 1) & 3)) << 3)]);
    }
    #pragma unroll
    for (int mt = 0; mt < 4; ++mt)
      #pragma unroll
      for (int nt = 0; nt < 3; ++nt)
        acc[mt][nt] = __builtin_amdgcn_mfma_f32_16x16x32_bf16(
            af[mt], bfr[nt], acc[mt][nt], 0, 0, 0);
  }

  if (bn < 16) {
    #pragma unroll
    for (int nt = 0; nt < 3; ++nt) {
      int col = bn * 96 + n_base + nt * 16 + l16;
      float bias = bq[col];
      #pragma unroll
      for (int mt = 0; mt < 4; ++mt) {
        int row = bm * 128 + m_base + mt * 16 + quad * 4;
        #pragma unroll
        for (int r = 0; r < 4; ++r) {
          __bf16 v = (__bf16)(acc[mt][nt][r] + bias);
          if (bn < 8) Qb[(row + r) * D + col] = v;
          else        Kb[(row + r) * D + (col - D)] = v;
        }
      }
    }
  } else {
    __syncthreads();
    __bf16* vts = smem;   // [w 96][t 128], addr = w*128 + (pos ^ ((w&7)<<3))
    #pragma unroll
    for (int nt = 0; nt < 3; ++nt) {
      int wl = n_base + nt * 16 + l16;
      float bias = bq[bn * 96 + wl];
      int sw = (wl & 7) << 3;
      #pragma unroll
      for (int mt = 0; mt < 4; ++mt) {
        #pragma unroll
        for (int r = 0; r < 4; ++r) {
          int tl = m_base + mt * 16 + quad * 4 + r;
          int pos = (tl & ~31) | (quad << 3) | ((tl & 16) >> 2) | r;
          vts[wl * 128 + (pos ^ sw)] = (__bf16)(acc[mt][nt][r] + bias);
        }
      }
    }
    __syncthreads();
    const int w0g = bn * 96 - 2 * D;
    #pragma unroll
    for (int it = 0; it < 6; ++it) {
      int c = it * 256 + tid;
      int wl = c >> 4, t0 = (c & 15) * 8;
      bf16x8 v = *reinterpret_cast<const bf16x8*>(
          &vts[wl * 128 + (t0 ^ ((wl & 7) << 3))]);
      *reinterpret_cast<bf16x8*>(
          &vT[(size_t)(w0g + wl) * S + bm * 128 + t0]) = v;
    }
  }
}

// ---------------------------------------------------------------------------
// Kernel 2: flash attention — R6 VERBATIM (best verified: 82.2us).
// 4 waves (2qh x 2th), K ping-pong LDS + single V LDS buffer via glds16,
// counted-vmcnt pipeline, direct pf packing, setprio around PV MFMA cluster.
// ---------------------------------------------------------------------------
__global__ __launch_bounds__(256)
void attention(const __bf16* __restrict__ Qb, const __bf16* __restrict__ Kb,
               const __bf16* __restrict__ vT, const float* __restrict__ mask,
               float* __restrict__ out)
{
  __shared__ char smem[49408];
  __bf16* Vt = (__bf16*)(smem + 32768);       // [64][128], swizzled+permuted-t
  float*  Ll = (float*)(smem + 49152);        // l partials (64 floats)
  float*  Lo = (float*)smem;                  // alias, end-reduction only

  const int tid  = threadIdx.x;
  const int wave = tid >> 6, lane = tid & 63;
  const int quad = lane >> 4, l16 = lane & 15;
  const int qh = wave >> 1;       // q-half
  const int th = wave & 1;        // t-half
  const int qb = blockIdx.x, h = blockIdx.y;
  const int q0 = qb * 64;
  const int qcol = h * 64;
  const int srow = lane >> 3, sg = lane & 7;
  const int vrow = lane >> 4, vs = lane & 15;

  bf16x8 qf[2][2];
  #pragma unroll
  for (int nt = 0; nt < 2; ++nt)
    #pragma unroll
    for (int kt = 0; kt < 2; ++kt)
      qf[nt][kt] = *reinterpret_cast<const bf16x8*>(
          Qb + (q0 + qh * 32 + nt * 16 + l16) * D + qcol + kt * 32 + quad * 8);

  floatx4 accO[4][2];
  #pragma unroll
  for (int wt = 0; wt < 4; ++wt)
    #pragma unroll
    for (int nt = 0; nt < 2; ++nt) accO[wt][nt] = (floatx4){0.f, 0.f, 0.f, 0.f};
  floatx4 accL[2];
  accL[0] = (floatx4){0.f, 0.f, 0.f, 0.f};
  accL[1] = (floatx4){0.f, 0.f, 0.f, 0.f};
  bf16x8 ones;
  #pragma unroll
  for (int e = 0; e < 8; ++e) ones[e] = (__bf16)1.0f;

  auto stageK = [&](int j, __bf16* dst) {
    #pragma unroll
    for (int it = 0; it < 4; ++it) {
      int rbase = it * 32 + wave * 8;
      int t = rbase + srow;
      glds16(Kb + (size_t)(j * 128 + t) * D + qcol + (sg ^ (t & 7)) * 8,
             dst + rbase * 64);
    }
  };
  auto stageV = [&](int j) {
    #pragma unroll
    for (int it = 0; it < 4; ++it) {
      int wbase = it * 16 + wave * 4;
      int w = wbase + vrow;
      glds16(vT + (size_t)(qcol + w) * S + j * 128 + (vs ^ (w & 7)) * 8,
             Vt + wbase * 128);
    }
  };

  // prologue: K(0), V(0) in flight
  stageK(0, (__bf16*)smem);
  stageV(0);

  for (int j = 0; j < 32; ++j) {
    // mask loads for this step (hoisted above the counted wait so the
    // compiler's mask-use wait drains V(j) but not K(j+1))
    floatx4 mv[4];
    #pragma unroll
    for (int mt = 0; mt < 4; ++mt)
      mv[mt] = *reinterpret_cast<const floatx4*>(
          mask + j * 128 + th * 64 + mt * 16 + quad * 4);

    asm volatile("s_waitcnt vmcnt(8)" ::: "memory");   // own K(j) drained
    __builtin_amdgcn_s_barrier();                      // B1: K(j) visible
    __builtin_amdgcn_sched_barrier(0);

    if (j < 31)                                        // prefetch next K
      stageK(j + 1, (__bf16*)(smem + (((j + 1) & 1) << 14)));
    __builtin_amdgcn_sched_barrier(0);

    const __bf16* Kc = (const __bf16*)(smem + ((j & 1) << 14));

    // S^T = K Q^T ; P = exp2(scale*S + mask2) packed DIRECTLY into pf.
    bf16x8 pf[2][2];
    #pragma unroll
    for (int mt = 0; mt < 4; ++mt) {
      int trow = th * 64 + mt * 16 + l16;
      bf16x8 kf[2];
      #pragma unroll
      for (int kt = 0; kt < 2; ++kt)
        kf[kt] = *reinterpret_cast<const bf16x8*>(
            &Kc[trow * 64 + ((((kt << 2) | quad) ^ (l16 & 7)) << 3)]);
      floatx4 am;   // (m-1)*10000*log2e ; exactly 0 when m==1
      #pragma unroll
      for (int r = 0; r < 4; ++r)
        am[r] = fmaf(mv[mt][r], 14426.9504f, -14426.9504f);
      #pragma unroll
      for (int nt = 0; nt < 2; ++nt) {
        floatx4 s = (floatx4){0.f, 0.f, 0.f, 0.f};
        #pragma unroll
        for (int kt = 0; kt < 2; ++kt)
          s = __builtin_amdgcn_mfma_f32_16x16x32_bf16(kf[kt], qf[nt][kt], s, 0, 0, 0);
        #pragma unroll
        for (int r = 0; r < 4; ++r)
          pf[mt >> 1][nt][(mt & 1) * 4 + r] = (__bf16)__builtin_amdgcn_exp2f(
              fmaf(s[r], 0.18033688f, am[r]));   // 0.125*log2e
      }
    }

    asm volatile("s_waitcnt vmcnt(4)" ::: "memory");   // V(j) drained; K(j+1) flies
    __builtin_amdgcn_s_barrier();                      // B_mid: V(j) visible
    __builtin_amdgcn_sched_barrier(0);

    // O^T += V^T P^T ; l via ones-MFMA. Pure-MFMA cluster -> setprio (T5).
    __builtin_amdgcn_s_setprio(1);
    #pragma unroll
    for (int u = 0; u < 2; ++u) {
      #pragma unroll
      for (int nt = 0; nt < 2; ++nt)
        accL[nt] = __builtin_amdgcn_mfma_f32_16x16x32_bf16(
            ones, pf[u][nt], accL[nt], 0, 0, 0);
      #pragma unroll
      for (int wt = 0; wt < 4; ++wt) {
        int w = wt * 16 + l16;
        bf16x8 vf = *reinterpret_cast<const bf16x8*>(
            &Vt[w * 128 + (((th * 8 + u * 4 + quad) ^ (w & 7)) << 3)]);
        #pragma unroll
        for (int nt = 0; nt < 2; ++nt)
          accO[wt][nt] = __builtin_amdgcn_mfma_f32_16x16x32_bf16(
              vf, pf[u][nt], accO[wt][nt], 0, 0, 0);
      }
    }
    __builtin_amdgcn_s_setprio(0);

    __builtin_amdgcn_s_barrier();                      // B2: Vt readers done
    __builtin_amdgcn_sched_barrier(0);
    if (j < 31) stageV(j + 1);                         // prefetch next V
    __builtin_amdgcn_sched_barrier(0);
  }

  // l for q = nt*16+l16 over this wave's 64 t: all 4 acc rows identical.
  float l_lane[2] = {accL[0][0], accL[1][0]};

  // ---- cross-wave reduction over t-halves ----
  __syncthreads();   // all Ks/Vt reads done; safe to alias Lo
  if (th == 1) {
    float* dst = Lo + qh * (64 * 33);
    #pragma unroll
    for (int wt = 0; wt < 4; ++wt)
      #pragma unroll
      for (int nt = 0; nt < 2; ++nt)
        #pragma unroll
        for (int r = 0; r < 4; ++r)
          dst[(wt * 16 + quad * 4 + r) * 33 + nt * 16 + l16] = accO[wt][nt][r];
    if (quad == 0) {
      #pragma unroll
      for (int nt = 0; nt < 2; ++nt)
        Ll[qh * 32 + nt * 16 + l16] = l_lane[nt];
    }
  }
  __syncthreads();
  if (th == 0) {
    const float* src = Lo + qh * (64 * 33);
    float l_tot[2];
    #pragma unroll
    for (int nt = 0; nt < 2; ++nt)
      l_tot[nt] = l_lane[nt] + Ll[qh * 32 + nt * 16 + l16];
    #pragma unroll
    for (int wt = 0; wt < 4; ++wt)
      #pragma unroll
      for (int nt = 0; nt < 2; ++nt) {
        floatx4 o;
        #pragma unroll
        for (int r = 0; r < 4; ++r)
          o[r] = (accO[wt][nt][r] +
                  src[(wt * 16 + quad * 4 + r) * 33 + nt * 16 + l16]) / l_tot[nt];
        int row = q0 + qh * 32 + nt * 16 + l16;
        int col = qcol + wt * 16 + quad * 4;
        *reinterpret_cast<floatx4*>(&out[row * D + col]) = o;
      }
  }
}

} // namespace

extern "C" void kernel_launch(void* const* d_in, const int* in_sizes, int n_in,
                              void* d_out, int out_size, void* d_ws, size_t ws_size,
                              hipStream_t stream) {
  const float *x = nullptr, *mask = nullptr, *Wq = nullptr, *bq = nullptr;
  for (int i = 0; i < n_in; ++i) {
    switch (in_sizes[i]) {
      case 3145728: x    = (const float*)d_in[i]; break;
      case 4096:    mask = (const float*)d_in[i]; break;
      case 1769472: Wq   = (const float*)d_in[i]; break;
      case 2304:    bq   = (const float*)d_in[i]; break;
      default: break;
    }
  }

  __bf16* xb = (__bf16*)d_out;               // bf16 scratch in d_out
  __bf16* WT = xb + (size_t)S * D;
  __bf16* Qb = (__bf16*)d_ws;
  __bf16* Kb = Qb + (size_t)S * D;
  __bf16* vT = Kb + (size_t)S * D;

  convert_all<<<3072 + 432, 256, 0, stream>>>(x, xb, Wq, WT);
  // --- TIMING PROBE (this round only): qkv_gemm dispatched 3x. It is
  // idempotent (reads xb/WT, writes identical Qb/Kb/vT each time), so
  // correctness is unaffected; (total - 165.1)/2 = one gemm's duration,
  // which rocprof's top-5 cannot otherwise reveal.
  qkv_gemm   <<<dim3(S / 128, N3 / 96), 256, 0, stream>>>(xb, WT, bq, Qb, Kb, vT);
  qkv_gemm   <<<dim3(S / 128, N3 / 96), 256, 0, stream>>>(xb, WT, bq, Qb, Kb, vT);
  qkv_gemm   <<<dim3(S / 128, N3 / 96), 256, 0, stream>>>(xb, WT, bq, Qb, Kb, vT);
  attention  <<<dim3(S / 64, H), 256, 0, stream>>>(Qb, Kb, vT, mask, (float*)d_out);
}

// Round 9
// 166.237 us; speedup vs baseline: 1.2575x; 1.2575x over previous
//
#include <hip/hip_runtime.h>
#include <hip/hip_bf16.h>
#include <hip/hip_cooperative_groups.h>

namespace cg = cooperative_groups;

namespace {
constexpr int S  = 4096;
constexpr int D  = 768;
constexpr int H  = 12;
constexpr int N3 = 2304;   // 3*D

typedef __bf16 bf16x4 __attribute__((ext_vector_type(4)));
typedef __bf16 bf16x8 __attribute__((ext_vector_type(8)));
typedef float  floatx4 __attribute__((ext_vector_type(4)));

// async global->LDS, 16B per lane; LDS dest = wave-uniform base + lane*16.
__device__ inline void glds16(const __bf16* g, __bf16* l) {
  __builtin_amdgcn_global_load_lds(
      (const __attribute__((address_space(1))) void*)(const void*)g,
      (__attribute__((address_space(3))) void*)(void*)l, 16, 0, 0);
}

// ===========================================================================
// FUSED single-dispatch pipeline (cooperative, grid = 768 = 3 blocks/CU):
//   phase 0: x fp32->bf16 (768 blk x 16 elem/thread) + W->WT transpose
//            (blocks 0..431, LDS-tiled)              -> grid.sync
//   phase 1: QKV GEMM (R7-validated body, bm=bid&31, bn=bid>>5) -> grid.sync
//   phase 2: flash attention (R6-validated body, qb=bid&63, h=bid>>6)
// Rationale (R8 probe): attention 84.6us + gemm ~22us leave ~58us of
// boundary/launch/drain overhead across 3 dispatches; all three grids are
// exactly 768 blocks and max LDS 49408B = exactly 3 blocks/CU, so the whole
// pipeline co-resides and the boundaries collapse into two grid.sync()s.
// __launch_bounds__(256,3) caps VGPR at 168 (live max ~100 -> no spill,
// R3 lesson) and guarantees the 3/CU occupancy the cooperative launch needs.
// grid.sync(): device-scope release/acquire = the cross-XCD L2 visibility
// that kernel boundaries provided; also drains vmcnt to 0, so phase 2's
// counted-vmcnt ledger starts clean.
// ===========================================================================
__global__ __launch_bounds__(256, 3)
void fused_all(const float* __restrict__ x, const float* __restrict__ mask,
               const float* __restrict__ W, const float* __restrict__ bq,
               float* __restrict__ out, __bf16* __restrict__ Qb,
               __bf16* __restrict__ Kb, __bf16* __restrict__ vT)
{
  __shared__ char smem[49408];
  const int bid = blockIdx.x;
  const int tid = threadIdx.x;
  __bf16* xb = (__bf16*)out;                 // bf16 scratch in d_out
  __bf16* WT = xb + (size_t)S * D;

  // ---------------- phase 0: converts ----------------
  {
    #pragma unroll
    for (int it = 0; it < 4; ++it) {
      int i = (it * 196608 + bid * 256 + tid) * 4;   // 196608 = 768*256
      floatx4 v = *reinterpret_cast<const floatx4*>(x + i);
      bf16x4 b;
      #pragma unroll
      for (int e = 0; e < 4; ++e) b[e] = (__bf16)v[e];
      *reinterpret_cast<bf16x4*>(xb + i) = b;
    }
    if (bid < 432) {
      float* T = (float*)smem;                       // [64][65]
      const int d0 = (bid % 12) * 64, e0 = (bid / 12) * 64;
      const int rr = tid >> 4, c4 = (tid & 15) * 4;
      #pragma unroll
      for (int it = 0; it < 4; ++it) {
        int d = it * 16 + rr;
        floatx4 v = *reinterpret_cast<const floatx4*>(W + (d0 + d) * N3 + e0 + c4);
        #pragma unroll
        for (int e = 0; e < 4; ++e) T[d * 65 + c4 + e] = v[e];
      }
      __syncthreads();
      #pragma unroll
      for (int it = 0; it < 4; ++it) {
        int e = it * 16 + rr;
        bf16x4 b;
        #pragma unroll
        for (int i2 = 0; i2 < 4; ++i2) b[i2] = (__bf16)T[(c4 + i2) * 65 + e];
        *reinterpret_cast<bf16x4*>(WT + (e0 + e) * D + d0 + c4) = b;
      }
    }
  }
  cg::this_grid().sync();

  // ---------------- phase 1: QKV GEMM (R7 body) ----------------
  {
    __bf16* gs = (__bf16*)smem;  // A0[4096] A1[4096] B0[3072] B1[3072]; vts
    const int wave = tid >> 6, lane = tid & 63;
    const int quad = lane >> 4, l16 = lane & 15;
    const int m_base = (wave >> 1) * 64;
    const int n_base = (wave & 1) * 48;
    const int bm = bid & 31, bn = bid >> 5;

    floatx4 acc[4][3];
    #pragma unroll
    for (int i = 0; i < 4; ++i)
      #pragma unroll
      for (int j = 0; j < 3; ++j) acc[i][j] = (floatx4){0.f, 0.f, 0.f, 0.f};

    auto stageA = [&](int k, int h) {
      #pragma unroll
      for (int it = 0; it < 2; ++it) {
        int r0 = it * 64 + wave * 16;
        int row = r0 + (lane >> 2);
        glds16(xb + (size_t)(bm * 128 + row) * D + k * 32
                  + (((lane & 3) ^ ((row >> 1) & 3)) * 8),
               gs + h * 4096 + r0 * 32);
      }
    };
    auto stageB = [&](int k, int h) {
      #pragma unroll
      for (int it = 0; it < 2; ++it) {
        int r0 = it * 64 + wave * 16;
        if (r0 < 96) {
          int row = r0 + (lane >> 2);
          glds16(WT + (size_t)(bn * 96 + row) * D + k * 32
                    + (((lane & 3) ^ ((row >> 1) & 3)) * 8),
                 gs + 8192 + h * 3072 + r0 * 32);
        }
      }
    };

    __builtin_amdgcn_sched_barrier(0);
    stageA(0, 0); stageB(0, 0);            // prologue
    __builtin_amdgcn_sched_barrier(0);

    for (int k = 0; k < 24; ++k) {
      const int h = k & 1;
      asm volatile("s_waitcnt vmcnt(0)" ::: "memory");   // stage(k) landed
      __builtin_amdgcn_s_barrier();                      // publish k
      __builtin_amdgcn_sched_barrier(0);

      if (k < 23) { stageA(k + 1, h ^ 1); stageB(k + 1, h ^ 1); }
      __builtin_amdgcn_sched_barrier(0);

      bf16x8 af[4], bfr[3];
      #pragma unroll
      for (int mt = 0; mt < 4; ++mt) {
        int m = m_base + mt * 16 + l16;
        af[mt] = *reinterpret_cast<const bf16x8*>(
            &gs[h * 4096 + m * 32 + ((quad ^ ((m >> 1) & 3)) << 3)]);
      }
      #pragma unroll
      for (int nt = 0; nt < 3; ++nt) {
        int n = n_base + nt * 16 + l16;
        bfr[nt] = *reinterpret_cast<const bf16x8*>(
            &gs[8192 + h * 3072 + n * 32 + ((quad ^ ((n >> 1) & 3)) << 3)]);
      }
      #pragma unroll
      for (int mt = 0; mt < 4; ++mt)
        #pragma unroll
        for (int nt = 0; nt < 3; ++nt)
          acc[mt][nt] = __builtin_amdgcn_mfma_f32_16x16x32_bf16(
              af[mt], bfr[nt], acc[mt][nt], 0, 0, 0);
    }

    if (bn < 16) {
      #pragma unroll
      for (int nt = 0; nt < 3; ++nt) {
        int col = bn * 96 + n_base + nt * 16 + l16;
        float bias = bq[col];
        #pragma unroll
        for (int mt = 0; mt < 4; ++mt) {
          int row = bm * 128 + m_base + mt * 16 + quad * 4;
          #pragma unroll
          for (int r = 0; r < 4; ++r) {
            __bf16 v = (__bf16)(acc[mt][nt][r] + bias);
            if (bn < 8) Qb[(row + r) * D + col] = v;
            else        Kb[(row + r) * D + (col - D)] = v;
          }
        }
      }
    } else {
      __syncthreads();
      __bf16* vts = gs;   // [w 96][t 128], addr = w*128 + (pos ^ ((w&7)<<3))
      #pragma unroll
      for (int nt = 0; nt < 3; ++nt) {
        int wl = n_base + nt * 16 + l16;
        float bias = bq[bn * 96 + wl];
        int sw = (wl & 7) << 3;
        #pragma unroll
        for (int mt = 0; mt < 4; ++mt) {
          #pragma unroll
          for (int r = 0; r < 4; ++r) {
            int tl = m_base + mt * 16 + quad * 4 + r;
            int pos = (tl & ~31) | (quad << 3) | ((tl & 16) >> 2) | r;
            vts[wl * 128 + (pos ^ sw)] = (__bf16)(acc[mt][nt][r] + bias);
          }
        }
      }
      __syncthreads();
      const int w0g = bn * 96 - 2 * D;
      #pragma unroll
      for (int it = 0; it < 6; ++it) {
        int c = it * 256 + tid;
        int wl = c >> 4, t0 = (c & 15) * 8;
        bf16x8 v = *reinterpret_cast<const bf16x8*>(
            &vts[wl * 128 + (t0 ^ ((wl & 7) << 3))]);
        *reinterpret_cast<bf16x8*>(
            &vT[(size_t)(w0g + wl) * S + bm * 128 + t0]) = v;
      }
    }
  }
  cg::this_grid().sync();

  // ---------------- phase 2: flash attention (R6 body) ----------------
  {
    __bf16* Vt = (__bf16*)(smem + 32768);     // [64][128], swizzled+permuted-t
    float*  Ll = (float*)(smem + 49152);      // l partials (64 floats)
    float*  Lo = (float*)smem;                // alias, end-reduction only

    const int wave = tid >> 6, lane = tid & 63;
    const int quad = lane >> 4, l16 = lane & 15;
    const int qh = wave >> 1;       // q-half
    const int th = wave & 1;        // t-half
    const int qb = bid & 63, h = bid >> 6;
    const int q0 = qb * 64;
    const int qcol = h * 64;
    const int srow = lane >> 3, sg = lane & 7;
    const int vrow = lane >> 4, vs = lane & 15;

    bf16x8 qf[2][2];
    #pragma unroll
    for (int nt = 0; nt < 2; ++nt)
      #pragma unroll
      for (int kt = 0; kt < 2; ++kt)
        qf[nt][kt] = *reinterpret_cast<const bf16x8*>(
            Qb + (q0 + qh * 32 + nt * 16 + l16) * D + qcol + kt * 32 + quad * 8);

    floatx4 accO[4][2];
    #pragma unroll
    for (int wt = 0; wt < 4; ++wt)
      #pragma unroll
      for (int nt = 0; nt < 2; ++nt) accO[wt][nt] = (floatx4){0.f, 0.f, 0.f, 0.f};
    floatx4 accL[2];
    accL[0] = (floatx4){0.f, 0.f, 0.f, 0.f};
    accL[1] = (floatx4){0.f, 0.f, 0.f, 0.f};
    bf16x8 ones;
    #pragma unroll
    for (int e = 0; e < 8; ++e) ones[e] = (__bf16)1.0f;

    auto stageK = [&](int j, __bf16* dst) {
      #pragma unroll
      for (int it = 0; it < 4; ++it) {
        int rbase = it * 32 + wave * 8;
        int t = rbase + srow;
        glds16(Kb + (size_t)(j * 128 + t) * D + qcol + (sg ^ (t & 7)) * 8,
               dst + rbase * 64);
      }
    };
    auto stageV = [&](int j) {
      #pragma unroll
      for (int it = 0; it < 4; ++it) {
        int wbase = it * 16 + wave * 4;
        int w = wbase + vrow;
        glds16(vT + (size_t)(qcol + w) * S + j * 128 + (vs ^ (w & 7)) * 8,
               Vt + wbase * 128);
      }
    };

    // prologue: K(0), V(0) in flight (vmcnt = 0 entering, grid.sync drained)
    stageK(0, (__bf16*)smem);
    stageV(0);

    for (int j = 0; j < 32; ++j) {
      floatx4 mv[4];
      #pragma unroll
      for (int mt = 0; mt < 4; ++mt)
        mv[mt] = *reinterpret_cast<const floatx4*>(
            mask + j * 128 + th * 64 + mt * 16 + quad * 4);

      asm volatile("s_waitcnt vmcnt(8)" ::: "memory");   // own K(j) drained
      __builtin_amdgcn_s_barrier();                      // B1: K(j) visible
      __builtin_amdgcn_sched_barrier(0);

      if (j < 31)
        stageK(j + 1, (__bf16*)(smem + (((j + 1) & 1) << 14)));
      __builtin_amdgcn_sched_barrier(0);

      const __bf16* Kc = (const __bf16*)(smem + ((j & 1) << 14));

      bf16x8 pf[2][2];
      #pragma unroll
      for (int mt = 0; mt < 4; ++mt) {
        int trow = th * 64 + mt * 16 + l16;
        bf16x8 kf[2];
        #pragma unroll
        for (int kt = 0; kt < 2; ++kt)
          kf[kt] = *reinterpret_cast<const bf16x8*>(
              &Kc[trow * 64 + ((((kt << 2) | quad) ^ (l16 & 7)) << 3)]);
        floatx4 am;   // (m-1)*10000*log2e ; exactly 0 when m==1
        #pragma unroll
        for (int r = 0; r < 4; ++r)
          am[r] = fmaf(mv[mt][r], 14426.9504f, -14426.9504f);
        #pragma unroll
        for (int nt = 0; nt < 2; ++nt) {
          floatx4 s = (floatx4){0.f, 0.f, 0.f, 0.f};
          #pragma unroll
          for (int kt = 0; kt < 2; ++kt)
            s = __builtin_amdgcn_mfma_f32_16x16x32_bf16(kf[kt], qf[nt][kt], s, 0, 0, 0);
          #pragma unroll
          for (int r = 0; r < 4; ++r)
            pf[mt >> 1][nt][(mt & 1) * 4 + r] = (__bf16)__builtin_amdgcn_exp2f(
                fmaf(s[r], 0.18033688f, am[r]));   // 0.125*log2e
        }
      }

      asm volatile("s_waitcnt vmcnt(4)" ::: "memory");   // V(j) drained
      __builtin_amdgcn_s_barrier();                      // B_mid: V(j) visible
      __builtin_amdgcn_sched_barrier(0);

      __builtin_amdgcn_s_setprio(1);
      #pragma unroll
      for (int u = 0; u < 2; ++u) {
        #pragma unroll
        for (int nt = 0; nt < 2; ++nt)
          accL[nt] = __builtin_amdgcn_mfma_f32_16x16x32_bf16(
              ones, pf[u][nt], accL[nt], 0, 0, 0);
        #pragma unroll
        for (int wt = 0; wt < 4; ++wt) {
          int w = wt * 16 + l16;
          bf16x8 vf = *reinterpret_cast<const bf16x8*>(
              &Vt[w * 128 + (((th * 8 + u * 4 + quad) ^ (w & 7)) << 3)]);
          #pragma unroll
          for (int nt = 0; nt < 2; ++nt)
            accO[wt][nt] = __builtin_amdgcn_mfma_f32_16x16x32_bf16(
                vf, pf[u][nt], accO[wt][nt], 0, 0, 0);
        }
      }
      __builtin_amdgcn_s_setprio(0);

      __builtin_amdgcn_s_barrier();                      // B2: Vt readers done
      __builtin_amdgcn_sched_barrier(0);
      if (j < 31) stageV(j + 1);
      __builtin_amdgcn_sched_barrier(0);
    }

    float l_lane[2] = {accL[0][0], accL[1][0]};

    __syncthreads();   // all Ks/Vt reads done; safe to alias Lo
    if (th == 1) {
      float* dst = Lo + qh * (64 * 33);
      #pragma unroll
      for (int wt = 0; wt < 4; ++wt)
        #pragma unroll
        for (int nt = 0; nt < 2; ++nt)
          #pragma unroll
          for (int r = 0; r < 4; ++r)
            dst[(wt * 16 + quad * 4 + r) * 33 + nt * 16 + l16] = accO[wt][nt][r];
      if (quad == 0) {
        #pragma unroll
        for (int nt = 0; nt < 2; ++nt)
          Ll[qh * 32 + nt * 16 + l16] = l_lane[nt];
      }
    }
    __syncthreads();
    if (th == 0) {
      const float* src = Lo + qh * (64 * 33);
      float l_tot[2];
      #pragma unroll
      for (int nt = 0; nt < 2; ++nt)
        l_tot[nt] = l_lane[nt] + Ll[qh * 32 + nt * 16 + l16];
      #pragma unroll
      for (int wt = 0; wt < 4; ++wt)
        #pragma unroll
        for (int nt = 0; nt < 2; ++nt) {
          floatx4 o;
          #pragma unroll
          for (int r = 0; r < 4; ++r)
            o[r] = (accO[wt][nt][r] +
                    src[(wt * 16 + quad * 4 + r) * 33 + nt * 16 + l16]) / l_tot[nt];
          int row = q0 + qh * 32 + nt * 16 + l16;
          int col = qcol + wt * 16 + quad * 4;
          *reinterpret_cast<floatx4*>(&out[row * D + col]) = o;
        }
    }
  }
}

// ===========================================================================
// Fallback path (R7-validated 3-kernel pipeline) — used only if the
// cooperative occupancy check fails. Bodies identical to R7.
// ===========================================================================
__global__ __launch_bounds__(256)
void convert_all(const float* __restrict__ x, __bf16* __restrict__ xb,
                 const float* __restrict__ W, __bf16* __restrict__ WT)
{
  const int bid = blockIdx.x;
  const int tid = threadIdx.x;
  if (bid < 3072) {
    const int i = (bid * 256 + tid) * 4;
    floatx4 v = *reinterpret_cast<const floatx4*>(x + i);
    bf16x4 b;
    #pragma unroll
    for (int e = 0; e < 4; ++e) b[e] = (__bf16)v[e];
    *reinterpret_cast<bf16x4*>(xb + i) = b;
  } else {
    __shared__ float T[64][65];
    const int b2 = bid - 3072;
    const int d0 = (b2 % 12) * 64, e0 = (b2 / 12) * 64;
    const int rr = tid >> 4, c4 = (tid & 15) * 4;
    #pragma unroll
    for (int it = 0; it < 4; ++it) {
      int d = it * 16 + rr;
      floatx4 v = *reinterpret_cast<const floatx4*>(W + (d0 + d) * N3 + e0 + c4);
      #pragma unroll
      for (int e = 0; e < 4; ++e) T[d][c4 + e] = v[e];
    }
    __syncthreads();
    #pragma unroll
    for (int it = 0; it < 4; ++it) {
      int e = it * 16 + rr;
      bf16x4 b;
      #pragma unroll
      for (int i = 0; i < 4; ++i) b[i] = (__bf16)T[c4 + i][e];
      *reinterpret_cast<bf16x4*>(WT + (e0 + e) * D + d0 + c4) = b;
    }
  }
}

__global__ __launch_bounds__(256)
void qkv_gemm(const __bf16* __restrict__ xb, const __bf16* __restrict__ WT,
              const float* __restrict__ bq, __bf16* __restrict__ Qb,
              __bf16* __restrict__ Kb, __bf16* __restrict__ vT)
{
  __shared__ __bf16 smem[14336];
  const int tid  = threadIdx.x;
  const int wave = tid >> 6, lane = tid & 63;
  const int quad = lane >> 4, l16 = lane & 15;
  const int m_base = (wave >> 1) * 64;
  const int n_base = (wave & 1) * 48;
  const int bm = blockIdx.x, bn = blockIdx.y;

  floatx4 acc[4][3];
  #pragma unroll
  for (int i = 0; i < 4; ++i)
    #pragma unroll
    for (int j = 0; j < 3; ++j) acc[i][j] = (floatx4){0.f, 0.f, 0.f, 0.f};

  auto stageA = [&](int k, int h) {
    #pragma unroll
    for (int it = 0; it < 2; ++it) {
      int r0 = it * 64 + wave * 16;
      int row = r0 + (lane >> 2);
      glds16(xb + (size_t)(bm * 128 + row) * D + k * 32
                + (((lane & 3) ^ ((row >> 1) & 3)) * 8),
             smem + h * 4096 + r0 * 32);
    }
  };
  auto stageB = [&](int k, int h) {
    #pragma unroll
    for (int it = 0; it < 2; ++it) {
      int r0 = it * 64 + wave * 16;
      if (r0 < 96) {
        int row = r0 + (lane >> 2);
        glds16(WT + (size_t)(bn * 96 + row) * D + k * 32
                  + (((lane & 3) ^ ((row >> 1) & 3)) * 8),
               smem + 8192 + h * 3072 + r0 * 32);
      }
    }
  };

  __builtin_amdgcn_sched_barrier(0);
  stageA(0, 0); stageB(0, 0);
  __builtin_amdgcn_sched_barrier(0);

  for (int k = 0; k < 24; ++k) {
    const int h = k & 1;
    asm volatile("s_waitcnt vmcnt(0)" ::: "memory");
    __builtin_amdgcn_s_barrier();
    __builtin_amdgcn_sched_barrier(0);

    if (k < 23) { stageA(k + 1, h ^ 1); stageB(k + 1, h ^ 1); }
    __builtin_amdgcn_sched_barrier(0);

    bf16x8 af[4], bfr[3];
    #pragma unroll
    for (int mt = 0; mt < 4; ++mt) {
      int m = m_base + mt * 16 + l16;
      af[mt] = *reinterpret_cast<const bf16x8*>(
          &smem[h * 4096 + m * 32 + ((quad ^ ((m >> 1) & 3)) << 3)]);
    }
    #pragma unroll
    for (int nt = 0; nt < 3; ++nt) {
      int n = n_base + nt * 16 + l16;
      bfr[nt] = *reinterpret_cast<const bf16x8*>(
          &smem[8192 + h * 3072 + n * 32 + ((quad ^ ((n >> 1) & 3)) << 3)]);
    }
    #pragma unroll
    for (int mt = 0; mt < 4; ++mt)
      #pragma unroll
      for (int nt = 0; nt < 3; ++nt)
        acc[mt][nt] = __builtin_amdgcn_mfma_f32_16x16x32_bf16(
            af[mt], bfr[nt], acc[mt][nt], 0, 0, 0);
  }

  if (bn < 16) {
    #pragma unroll
    for (int nt = 0; nt < 3; ++nt) {
      int col = bn * 96 + n_base + nt * 16 + l16;
      float bias = bq[col];
      #pragma unroll
      for (int mt = 0; mt < 4; ++mt) {
        int row = bm * 128 + m_base + mt * 16 + quad * 4;
        #pragma unroll
        for (int r = 0; r < 4; ++r) {
          __bf16 v = (__bf16)(acc[mt][nt][r] + bias);
          if (bn < 8) Qb[(row + r) * D + col] = v;
          else        Kb[(row + r) * D + (col - D)] = v;
        }
      }
    }
  } else {
    __syncthreads();
    __bf16* vts = smem;
    #pragma unroll
    for (int nt = 0; nt < 3; ++nt) {
      int wl = n_base + nt * 16 + l16;
      float bias = bq[bn * 96 + wl];
      int sw = (wl & 7) << 3;
      #pragma unroll
      for (int mt = 0; mt < 4; ++mt) {
        #pragma unroll
        for (int r = 0; r < 4; ++r) {
          int tl = m_base + mt * 16 + quad * 4 + r;
          int pos = (tl & ~31) | (quad << 3) | ((tl & 16) >> 2) | r;
          vts[wl * 128 + (pos ^ sw)] = (__bf16)(acc[mt][nt][r] + bias);
        }
      }
    }
    __syncthreads();
    const int w0g = bn * 96 - 2 * D;
    #pragma unroll
    for (int it = 0; it < 6; ++it) {
      int c = it * 256 + tid;
      int wl = c >> 4, t0 = (c & 15) * 8;
      bf16x8 v = *reinterpret_cast<const bf16x8*>(
          &vts[wl * 128 + (t0 ^ ((wl & 7) << 3))]);
      *reinterpret_cast<bf16x8*>(
          &vT[(size_t)(w0g + wl) * S + bm * 128 + t0]) = v;
    }
  }
}

__global__ __launch_bounds__(256)
void attention(const __bf16* __restrict__ Qb, const __bf16* __restrict__ Kb,
               const __bf16* __restrict__ vT, const float* __restrict__ mask,
               float* __restrict__ out)
{
  __shared__ char smem[49408];
  __bf16* Vt = (__bf16*)(smem + 32768);
  float*  Ll = (float*)(smem + 49152);
  float*  Lo = (float*)smem;

  const int tid  = threadIdx.x;
  const int wave = tid >> 6, lane = tid & 63;
  const int quad = lane >> 4, l16 = lane & 15;
  const int qh = wave >> 1;
  const int th = wave & 1;
  const int qb = blockIdx.x, h = blockIdx.y;
  const int q0 = qb * 64;
  const int qcol = h * 64;
  const int srow = lane >> 3, sg = lane & 7;
  const int vrow = lane >> 4, vs = lane & 15;

  bf16x8 qf[2][2];
  #pragma unroll
  for (int nt = 0; nt < 2; ++nt)
    #pragma unroll
    for (int kt = 0; kt < 2; ++kt)
      qf[nt][kt] = *reinterpret_cast<const bf16x8*>(
          Qb + (q0 + qh * 32 + nt * 16 + l16) * D + qcol + kt * 32 + quad * 8);

  floatx4 accO[4][2];
  #pragma unroll
  for (int wt = 0; wt < 4; ++wt)
    #pragma unroll
    for (int nt = 0; nt < 2; ++nt) accO[wt][nt] = (floatx4){0.f, 0.f, 0.f, 0.f};
  floatx4 accL[2];
  accL[0] = (floatx4){0.f, 0.f, 0.f, 0.f};
  accL[1] = (floatx4){0.f, 0.f, 0.f, 0.f};
  bf16x8 ones;
  #pragma unroll
  for (int e = 0; e < 8; ++e) ones[e] = (__bf16)1.0f;

  auto stageK = [&](int j, __bf16* dst) {
    #pragma unroll
    for (int it = 0; it < 4; ++it) {
      int rbase = it * 32 + wave * 8;
      int t = rbase + srow;
      glds16(Kb + (size_t)(j * 128 + t) * D + qcol + (sg ^ (t & 7)) * 8,
             dst + rbase * 64);
    }
  };
  auto stageV = [&](int j) {
    #pragma unroll
    for (int it = 0; it < 4; ++it) {
      int wbase = it * 16 + wave * 4;
      int w = wbase + vrow;
      glds16(vT + (size_t)(qcol + w) * S + j * 128 + (vs ^ (w & 7)) * 8,
             Vt + wbase * 128);
    }
  };

  stageK(0, (__bf16*)smem);
  stageV(0);

  for (int j = 0; j < 32; ++j) {
    floatx4 mv[4];
    #pragma unroll
    for (int mt = 0; mt < 4; ++mt)
      mv[mt] = *reinterpret_cast<const floatx4*>(
          mask + j * 128 + th * 64 + mt * 16 + quad * 4);

    asm volatile("s_waitcnt vmcnt(8)" ::: "memory");
    __builtin_amdgcn_s_barrier();
    __builtin_amdgcn_sched_barrier(0);

    if (j < 31)
      stageK(j + 1, (__bf16*)(smem + (((j + 1) & 1) << 14)));
    __builtin_amdgcn_sched_barrier(0);

    const __bf16* Kc = (const __bf16*)(smem + ((j & 1) << 14));

    bf16x8 pf[2][2];
    #pragma unroll
    for (int mt = 0; mt < 4; ++mt) {
      int trow = th * 64 + mt * 16 + l16;
      bf16x8 kf[2];
      #pragma unroll
      for (int kt = 0; kt < 2; ++kt)
        kf[kt] = *reinterpret_cast<const bf16x8*>(
            &Kc[trow * 64 + ((((kt << 2) | quad) ^ (l16 & 7)) << 3)]);
      floatx4 am;
      #pragma unroll
      for (int r = 0; r < 4; ++r)
        am[r] = fmaf(mv[mt][r], 14426.9504f, -14426.9504f);
      #pragma unroll
      for (int nt = 0; nt < 2; ++nt) {
        floatx4 s = (floatx4){0.f, 0.f, 0.f, 0.f};
        #pragma unroll
        for (int kt = 0; kt < 2; ++kt)
          s = __builtin_amdgcn_mfma_f32_16x16x32_bf16(kf[kt], qf[nt][kt], s, 0, 0, 0);
        #pragma unroll
        for (int r = 0; r < 4; ++r)
          pf[mt >> 1][nt][(mt & 1) * 4 + r] = (__bf16)__builtin_amdgcn_exp2f(
              fmaf(s[r], 0.18033688f, am[r]));
      }
    }

    asm volatile("s_waitcnt vmcnt(4)" ::: "memory");
    __builtin_amdgcn_s_barrier();
    __builtin_amdgcn_sched_barrier(0);

    __builtin_amdgcn_s_setprio(1);
    #pragma unroll
    for (int u = 0; u < 2; ++u) {
      #pragma unroll
      for (int nt = 0; nt < 2; ++nt)
        accL[nt] = __builtin_amdgcn_mfma_f32_16x16x32_bf16(
            ones, pf[u][nt], accL[nt], 0, 0, 0);
      #pragma unroll
      for (int wt = 0; wt < 4; ++wt) {
        int w = wt * 16 + l16;
        bf16x8 vf = *reinterpret_cast<const bf16x8*>(
            &Vt[w * 128 + (((th * 8 + u * 4 + quad) ^ (w & 7)) << 3)]);
        #pragma unroll
        for (int nt = 0; nt < 2; ++nt)
          accO[wt][nt] = __builtin_amdgcn_mfma_f32_16x16x32_bf16(
              vf, pf[u][nt], accO[wt][nt], 0, 0, 0);
      }
    }
    __builtin_amdgcn_s_setprio(0);

    __builtin_amdgcn_s_barrier();
    __builtin_amdgcn_sched_barrier(0);
    if (j < 31) stageV(j + 1);
    __builtin_amdgcn_sched_barrier(0);
  }

  float l_lane[2] = {accL[0][0], accL[1][0]};

  __syncthreads();
  if (th == 1) {
    float* dst = Lo + qh * (64 * 33);
    #pragma unroll
    for (int wt = 0; wt < 4; ++wt)
      #pragma unroll
      for (int nt = 0; nt < 2; ++nt)
        #pragma unroll
        for (int r = 0; r < 4; ++r)
          dst[(wt * 16 + quad * 4 + r) * 33 + nt * 16 + l16] = accO[wt][nt][r];
    if (quad == 0) {
      #pragma unroll
      for (int nt = 0; nt < 2; ++nt)
        Ll[qh * 32 + nt * 16 + l16] = l_lane[nt];
    }
  }
  __syncthreads();
  if (th == 0) {
    const float* src = Lo + qh * (64 * 33);
    float l_tot[2];
    #pragma unroll
    for (int nt = 0; nt < 2; ++nt)
      l_tot[nt] = l_lane[nt] + Ll[qh * 32 + nt * 16 + l16];
    #pragma unroll
    for (int wt = 0; wt < 4; ++wt)
      #pragma unroll
      for (int nt = 0; nt < 2; ++nt) {
        floatx4 o;
        #pragma unroll
        for (int r = 0; r < 4; ++r)
          o[r] = (accO[wt][nt][r] +
                  src[(wt * 16 + quad * 4 + r) * 33 + nt * 16 + l16]) / l_tot[nt];
        int row = q0 + qh * 32 + nt * 16 + l16;
        int col = qcol + wt * 16 + quad * 4;
        *reinterpret_cast<floatx4*>(&out[row * D + col]) = o;
      }
  }
}

} // namespace

extern "C" void kernel_launch(void* const* d_in, const int* in_sizes, int n_in,
                              void* d_out, int out_size, void* d_ws, size_t ws_size,
                              hipStream_t stream) {
  const float *x = nullptr, *mask = nullptr, *Wq = nullptr, *bq = nullptr;
  for (int i = 0; i < n_in; ++i) {
    switch (in_sizes[i]) {
      case 3145728: x    = (const float*)d_in[i]; break;
      case 4096:    mask = (const float*)d_in[i]; break;
      case 1769472: Wq   = (const float*)d_in[i]; break;
      case 2304:    bq   = (const float*)d_in[i]; break;
      default: break;
    }
  }

  __bf16* xb = (__bf16*)d_out;               // bf16 scratch in d_out
  __bf16* WT = xb + (size_t)S * D;
  __bf16* Qb = (__bf16*)d_ws;
  __bf16* Kb = Qb + (size_t)S * D;
  __bf16* vT = Kb + (size_t)S * D;
  float*  outp = (float*)d_out;

  // One-time host-side occupancy check (pure query, graph-capture-safe):
  // the cooperative launch needs all 768 blocks co-resident (3 blocks/CU).
  static int coop_ok = -1;
  if (coop_ok < 0) {
    int nb = 0;
    if (hipOccupancyMaxActiveBlocksPerMultiprocessor(
            &nb, (const void*)fused_all, 256, 0) != hipSuccess) nb = 0;
    coop_ok = (nb >= 3) ? 1 : 0;
  }

  if (coop_ok) {
    void* kargs[] = {(void*)&x, (void*)&mask, (void*)&Wq, (void*)&bq,
                     (void*)&outp, (void*)&Qb, (void*)&Kb, (void*)&vT};
    hipLaunchCooperativeKernel((const void*)fused_all, dim3(768), dim3(256),
                               kargs, 0, stream);
  } else {
    // R7-validated 3-kernel fallback.
    convert_all<<<3072 + 432, 256, 0, stream>>>(x, xb, Wq, WT);
    qkv_gemm   <<<dim3(S / 128, N3 / 96), 256, 0, stream>>>(xb, WT, bq, Qb, Kb, vT);
    attention  <<<dim3(S / 64, H), 256, 0, stream>>>(Qb, Kb, vT, mask, (float*)d_out);
  }
}

// Round 10
// 160.587 us; speedup vs baseline: 1.3017x; 1.0352x over previous
//
#include <hip/hip_runtime.h>
#include <hip/hip_bf16.h>

namespace {
constexpr int S  = 4096;
constexpr int D  = 768;
constexpr int H  = 12;
constexpr int N3 = 2304;   // 3*D

typedef __bf16 bf16x4 __attribute__((ext_vector_type(4)));
typedef __bf16 bf16x8 __attribute__((ext_vector_type(8)));
typedef float  floatx4 __attribute__((ext_vector_type(4)));

// async global->LDS, 16B per lane; LDS dest = wave-uniform base + lane*16.
__device__ inline void glds16(const __bf16* g, __bf16* l) {
  __builtin_amdgcn_global_load_lds(
      (const __attribute__((address_space(1))) void*)(const void*)g,
      (__attribute__((address_space(3))) void*)(void*)l, 16, 0, 0);
}

// ---------------------------------------------------------------------------
// Kernel 0: merged converts (R7 verbatim).
// ---------------------------------------------------------------------------
__global__ __launch_bounds__(256)
void convert_all(const float* __restrict__ x, __bf16* __restrict__ xb,
                 const float* __restrict__ W, __bf16* __restrict__ WT)
{
  const int bid = blockIdx.x;
  const int tid = threadIdx.x;
  if (bid < 3072) {
    const int i = (bid * 256 + tid) * 4;
    floatx4 v = *reinterpret_cast<const floatx4*>(x + i);
    bf16x4 b;
    #pragma unroll
    for (int e = 0; e < 4; ++e) b[e] = (__bf16)v[e];
    *reinterpret_cast<bf16x4*>(xb + i) = b;
  } else {
    __shared__ float T[64][65];
    const int b2 = bid - 3072;
    const int d0 = (b2 % 12) * 64, e0 = (b2 / 12) * 64;
    const int rr = tid >> 4, c4 = (tid & 15) * 4;
    #pragma unroll
    for (int it = 0; it < 4; ++it) {
      int d = it * 16 + rr;
      floatx4 v = *reinterpret_cast<const floatx4*>(W + (d0 + d) * N3 + e0 + c4);
      #pragma unroll
      for (int e = 0; e < 4; ++e) T[d][c4 + e] = v[e];
    }
    __syncthreads();
    #pragma unroll
    for (int it = 0; it < 4; ++it) {
      int e = it * 16 + rr;
      bf16x4 b;
      #pragma unroll
      for (int i = 0; i < 4; ++i) b[i] = (__bf16)T[c4 + i][e];
      *reinterpret_cast<bf16x4*>(WT + (e0 + e) * D + d0 + c4) = b;
    }
  }
}

// ---------------------------------------------------------------------------
// Kernel 1: QKV GEMM (R7 verbatim: BK=32 in-place dbuf, 1 barrier/step).
// ---------------------------------------------------------------------------
__global__ __launch_bounds__(256)
void qkv_gemm(const __bf16* __restrict__ xb, const __bf16* __restrict__ WT,
              const float* __restrict__ bq, __bf16* __restrict__ Qb,
              __bf16* __restrict__ Kb, __bf16* __restrict__ vT)
{
  __shared__ __bf16 smem[14336];
  const int tid  = threadIdx.x;
  const int wave = tid >> 6, lane = tid & 63;
  const int quad = lane >> 4, l16 = lane & 15;
  const int m_base = (wave >> 1) * 64;
  const int n_base = (wave & 1) * 48;
  const int bm = blockIdx.x, bn = blockIdx.y;

  floatx4 acc[4][3];
  #pragma unroll
  for (int i = 0; i < 4; ++i)
    #pragma unroll
    for (int j = 0; j < 3; ++j) acc[i][j] = (floatx4){0.f, 0.f, 0.f, 0.f};

  auto stageA = [&](int k, int h) {
    #pragma unroll
    for (int it = 0; it < 2; ++it) {
      int r0 = it * 64 + wave * 16;
      int row = r0 + (lane >> 2);
      glds16(xb + (size_t)(bm * 128 + row) * D + k * 32
                + (((lane & 3) ^ ((row >> 1) & 3)) * 8),
             smem + h * 4096 + r0 * 32);
    }
  };
  auto stageB = [&](int k, int h) {
    #pragma unroll
    for (int it = 0; it < 2; ++it) {
      int r0 = it * 64 + wave * 16;
      if (r0 < 96) {
        int row = r0 + (lane >> 2);
        glds16(WT + (size_t)(bn * 96 + row) * D + k * 32
                  + (((lane & 3) ^ ((row >> 1) & 3)) * 8),
               smem + 8192 + h * 3072 + r0 * 32);
      }
    }
  };

  __builtin_amdgcn_sched_barrier(0);
  stageA(0, 0); stageB(0, 0);
  __builtin_amdgcn_sched_barrier(0);

  for (int k = 0; k < 24; ++k) {
    const int h = k & 1;
    asm volatile("s_waitcnt vmcnt(0)" ::: "memory");
    __builtin_amdgcn_s_barrier();
    __builtin_amdgcn_sched_barrier(0);

    if (k < 23) { stageA(k + 1, h ^ 1); stageB(k + 1, h ^ 1); }
    __builtin_amdgcn_sched_barrier(0);

    bf16x8 af[4], bfr[3];
    #pragma unroll
    for (int mt = 0; mt < 4; ++mt) {
      int m = m_base + mt * 16 + l16;
      af[mt] = *reinterpret_cast<const bf16x8*>(
          &smem[h * 4096 + m * 32 + ((quad ^ ((m >> 1) & 3)) << 3)]);
    }
    #pragma unroll
    for (int nt = 0; nt < 3; ++nt) {
      int n = n_base + nt * 16 + l16;
      bfr[nt] = *reinterpret_cast<const bf16x8*>(
          &smem[8192 + h * 3072 + n * 32 + ((quad ^ ((n >> 1) & 3)) << 3)]);
    }
    #pragma unroll
    for (int mt = 0; mt < 4; ++mt)
      #pragma unroll
      for (int nt = 0; nt < 3; ++nt)
        acc[mt][nt] = __builtin_amdgcn_mfma_f32_16x16x32_bf16(
            af[mt], bfr[nt], acc[mt][nt], 0, 0, 0);
  }

  if (bn < 16) {
    #pragma unroll
    for (int nt = 0; nt < 3; ++nt) {
      int col = bn * 96 + n_base + nt * 16 + l16;
      float bias = bq[col];
      #pragma unroll
      for (int mt = 0; mt < 4; ++mt) {
        int row = bm * 128 + m_base + mt * 16 + quad * 4;
        #pragma unroll
        for (int r = 0; r < 4; ++r) {
          __bf16 v = (__bf16)(acc[mt][nt][r] + bias);
          if (bn < 8) Qb[(row + r) * D + col] = v;
          else        Kb[(row + r) * D + (col - D)] = v;
        }
      }
    }
  } else {
    __syncthreads();
    __bf16* vts = smem;
    #pragma unroll
    for (int nt = 0; nt < 3; ++nt) {
      int wl = n_base + nt * 16 + l16;
      float bias = bq[bn * 96 + wl];
      int sw = (wl & 7) << 3;
      #pragma unroll
      for (int mt = 0; mt < 4; ++mt) {
        #pragma unroll
        for (int r = 0; r < 4; ++r) {
          int tl = m_base + mt * 16 + quad * 4 + r;
          int pos = (tl & ~31) | (quad << 3) | ((tl & 16) >> 2) | r;
          vts[wl * 128 + (pos ^ sw)] = (__bf16)(acc[mt][nt][r] + bias);
        }
      }
    }
    __syncthreads();
    const int w0g = bn * 96 - 2 * D;
    #pragma unroll
    for (int it = 0; it < 6; ++it) {
      int c = it * 256 + tid;
      int wl = c >> 4, t0 = (c & 15) * 8;
      bf16x8 v = *reinterpret_cast<const bf16x8*>(
          &vts[wl * 128 + (t0 ^ ((wl & 7) << 3))]);
      *reinterpret_cast<bf16x8*>(
          &vT[(size_t)(w0g + wl) * S + bm * 128 + t0]) = v;
    }
  }
}

// ---------------------------------------------------------------------------
// Kernel 2: flash attention — R6 structure with VALU-overhead reduction:
//  (a) j-loop unrolled x2 with COMPILE-TIME ping-pong K bases (B0/B1 passed
//      statically to the step body) — kills the runtime (j&1)<<14 base select
//      and lets LICM hoist all LDS fragment offsets out of the loop.
//  (b) Global addressing strength-reduced: per-lane invariant bases pK/pV/pM
//      (the XOR swizzles are j/it-invariant: t&7 = srow&7 since rbase is a
//      multiple of 8; w&7 = (wave*4+vrow)&7 since it*16 is a multiple of 8)
//      plus j*stride offsets the unrolled loop strength-reduces.
//  (c) __launch_bounds__(256, 3): VGPR budget 170. Occupancy is pinned at
//      3 waves/SIMD by LDS (49408B -> 3 blocks/CU) regardless, so the wider
//      budget is free — it licenses the register allocator to keep hoisted
//      addresses live instead of rematerializing (R9 theory: ~600 of the
//      ~1020 VALU-cyc/wave-step are recomputed addressing at VGPR=80).
//      NOT an R3 repeat: budget 170 >> live state ~110.
//  Pipeline/barrier/vmcnt structure untouched (ledger identical to R6/R7).
// ---------------------------------------------------------------------------
__global__ __launch_bounds__(256, 3)
void attention(const __bf16* __restrict__ Qb, const __bf16* __restrict__ Kb,
               const __bf16* __restrict__ vT, const float* __restrict__ mask,
               float* __restrict__ out)
{
  __shared__ char smem[49408];
  __bf16* B0 = (__bf16*)smem;                 // K ping buffer [128][64] swz
  __bf16* B1 = (__bf16*)(smem + 16384);       // K pong buffer
  __bf16* Vt = (__bf16*)(smem + 32768);       // [64][128], swizzled+permuted-t
  float*  Ll = (float*)(smem + 49152);        // l partials (64 floats)
  float*  Lo = (float*)smem;                  // alias, end-reduction only

  const int tid  = threadIdx.x;
  const int wave = tid >> 6, lane = tid & 63;
  const int quad = lane >> 4, l16 = lane & 15;
  const int qh = wave >> 1;       // q-half
  const int th = wave & 1;        // t-half
  const int qb = blockIdx.x, h = blockIdx.y;
  const int q0 = qb * 64;
  const int qcol = h * 64;
  const int srow = lane >> 3, sg = lane & 7;
  const int vrow = lane >> 4, vs = lane & 15;

  // per-lane invariant staging bases (swizzles proven j/it-invariant)
  const int swzK = (sg ^ (srow & 7)) * 8;
  const int swzV = (vs ^ ((wave * 4 + vrow) & 7)) * 8;
  const __bf16* pK = Kb + qcol + (size_t)(wave * 8 + srow) * D + swzK;
  const __bf16* pV = vT + (size_t)(qcol + wave * 4 + vrow) * S + swzV;
  const float*  pM = mask + th * 64 + quad * 4;

  bf16x8 qf[2][2];
  #pragma unroll
  for (int nt = 0; nt < 2; ++nt)
    #pragma unroll
    for (int kt = 0; kt < 2; ++kt)
      qf[nt][kt] = *reinterpret_cast<const bf16x8*>(
          Qb + (q0 + qh * 32 + nt * 16 + l16) * D + qcol + kt * 32 + quad * 8);

  floatx4 accO[4][2];
  #pragma unroll
  for (int wt = 0; wt < 4; ++wt)
    #pragma unroll
    for (int nt = 0; nt < 2; ++nt) accO[wt][nt] = (floatx4){0.f, 0.f, 0.f, 0.f};
  floatx4 accL[2];
  accL[0] = (floatx4){0.f, 0.f, 0.f, 0.f};
  accL[1] = (floatx4){0.f, 0.f, 0.f, 0.f};
  bf16x8 ones;
  #pragma unroll
  for (int e = 0; e < 8; ++e) ones[e] = (__bf16)1.0f;

  auto stageK2 = [&](const __bf16* src, __bf16* dst) {
    #pragma unroll
    for (int it = 0; it < 4; ++it)
      glds16(src + (size_t)it * 32 * D, dst + (it * 32 + wave * 8) * 64);
  };
  auto stageV2 = [&](const __bf16* src) {
    #pragma unroll
    for (int it = 0; it < 4; ++it)
      glds16(src + (size_t)it * 16 * S, Vt + (it * 16 + wave * 4) * 128);
  };

  // prologue: K(0), V(0) in flight
  stageK2(pK, B0);
  stageV2(pV);

  // one pipeline step; Kc/Kn are COMPILE-TIME buffer pointers.
  auto step = [&](int j, const __bf16* Kc, __bf16* Kn, bool stage_next) {
    floatx4 mv[4];
    #pragma unroll
    for (int mt = 0; mt < 4; ++mt)
      mv[mt] = *reinterpret_cast<const floatx4*>(pM + (size_t)j * 128 + mt * 16);

    asm volatile("s_waitcnt vmcnt(8)" ::: "memory");   // own K(j) drained
    __builtin_amdgcn_s_barrier();                      // B1: K(j) visible
    __builtin_amdgcn_sched_barrier(0);

    if (stage_next) stageK2(pK + (size_t)(j + 1) * 128 * D, Kn);
    __builtin_amdgcn_sched_barrier(0);

    // S^T = K Q^T ; P = exp2(scale*S + mask2) packed DIRECTLY into pf.
    bf16x8 pf[2][2];
    #pragma unroll
    for (int mt = 0; mt < 4; ++mt) {
      int trow = th * 64 + mt * 16 + l16;
      bf16x8 kf[2];
      #pragma unroll
      for (int kt = 0; kt < 2; ++kt)
        kf[kt] = *reinterpret_cast<const bf16x8*>(
            &Kc[trow * 64 + ((((kt << 2) | quad) ^ (l16 & 7)) << 3)]);
      floatx4 am;   // (m-1)*10000*log2e ; exactly 0 when m==1
      #pragma unroll
      for (int r = 0; r < 4; ++r)
        am[r] = fmaf(mv[mt][r], 14426.9504f, -14426.9504f);
      #pragma unroll
      for (int nt = 0; nt < 2; ++nt) {
        floatx4 s = (floatx4){0.f, 0.f, 0.f, 0.f};
        #pragma unroll
        for (int kt = 0; kt < 2; ++kt)
          s = __builtin_amdgcn_mfma_f32_16x16x32_bf16(kf[kt], qf[nt][kt], s, 0, 0, 0);
        #pragma unroll
        for (int r = 0; r < 4; ++r)
          pf[mt >> 1][nt][(mt & 1) * 4 + r] = (__bf16)__builtin_amdgcn_exp2f(
              fmaf(s[r], 0.18033688f, am[r]));   // 0.125*log2e
      }
    }

    asm volatile("s_waitcnt vmcnt(4)" ::: "memory");   // V(j) drained
    __builtin_amdgcn_s_barrier();                      // B_mid: V(j) visible
    __builtin_amdgcn_sched_barrier(0);

    // O^T += V^T P^T ; l via ones-MFMA. Pure-MFMA cluster -> setprio (T5).
    __builtin_amdgcn_s_setprio(1);
    #pragma unroll
    for (int u = 0; u < 2; ++u) {
      #pragma unroll
      for (int nt = 0; nt < 2; ++nt)
        accL[nt] = __builtin_amdgcn_mfma_f32_16x16x32_bf16(
            ones, pf[u][nt], accL[nt], 0, 0, 0);
      #pragma unroll
      for (int wt = 0; wt < 4; ++wt) {
        int w = wt * 16 + l16;
        bf16x8 vf = *reinterpret_cast<const bf16x8*>(
            &Vt[w * 128 + (((th * 8 + u * 4 + quad) ^ (w & 7)) << 3)]);
        #pragma unroll
        for (int nt = 0; nt < 2; ++nt)
          accO[wt][nt] = __builtin_amdgcn_mfma_f32_16x16x32_bf16(
              vf, pf[u][nt], accO[wt][nt], 0, 0, 0);
      }
    }
    __builtin_amdgcn_s_setprio(0);

    __builtin_amdgcn_s_barrier();                      // B2: Vt readers done
    __builtin_amdgcn_sched_barrier(0);
    if (stage_next) stageV2(pV + (size_t)(j + 1) * 128);
    __builtin_amdgcn_sched_barrier(0);
  };

  for (int jj = 0; jj < 32; jj += 2) {
    step(jj,     B0, B1, true);          // jj <= 30, so j+1 <= 31 always valid
    step(jj + 1, B1, B0, jj + 1 < 31);   // j=31: no prefetch
  }

  // l for q = nt*16+l16 over this wave's 64 t: all 4 acc rows identical.
  float l_lane[2] = {accL[0][0], accL[1][0]};

  // ---- cross-wave reduction over t-halves ----
  __syncthreads();   // all Ks/Vt reads done; safe to alias Lo
  if (th == 1) {
    float* dst = Lo + qh * (64 * 33);
    #pragma unroll
    for (int wt = 0; wt < 4; ++wt)
      #pragma unroll
      for (int nt = 0; nt < 2; ++nt)
        #pragma unroll
        for (int r = 0; r < 4; ++r)
          dst[(wt * 16 + quad * 4 + r) * 33 + nt * 16 + l16] = accO[wt][nt][r];
    if (quad == 0) {
      #pragma unroll
      for (int nt = 0; nt < 2; ++nt)
        Ll[qh * 32 + nt * 16 + l16] = l_lane[nt];
    }
  }
  __syncthreads();
  if (th == 0) {
    const float* src = Lo + qh * (64 * 33);
    float l_tot[2];
    #pragma unroll
    for (int nt = 0; nt < 2; ++nt)
      l_tot[nt] = l_lane[nt] + Ll[qh * 32 + nt * 16 + l16];
    #pragma unroll
    for (int wt = 0; wt < 4; ++wt)
      #pragma unroll
      for (int nt = 0; nt < 2; ++nt) {
        floatx4 o;
        #pragma unroll
        for (int r = 0; r < 4; ++r)
          o[r] = (accO[wt][nt][r] +
                  src[(wt * 16 + quad * 4 + r) * 33 + nt * 16 + l16]) / l_tot[nt];
        int row = q0 + qh * 32 + nt * 16 + l16;
        int col = qcol + wt * 16 + quad * 4;
        *reinterpret_cast<floatx4*>(&out[row * D + col]) = o;
      }
  }
}

} // namespace

extern "C" void kernel_launch(void* const* d_in, const int* in_sizes, int n_in,
                              void* d_out, int out_size, void* d_ws, size_t ws_size,
                              hipStream_t stream) {
  const float *x = nullptr, *mask = nullptr, *Wq = nullptr, *bq = nullptr;
  for (int i = 0; i < n_in; ++i) {
    switch (in_sizes[i]) {
      case 3145728: x    = (const float*)d_in[i]; break;
      case 4096:    mask = (const float*)d_in[i]; break;
      case 1769472: Wq   = (const float*)d_in[i]; break;
      case 2304:    bq   = (const float*)d_in[i]; break;
      default: break;
    }
  }

  __bf16* xb = (__bf16*)d_out;               // bf16 scratch in d_out
  __bf16* WT = xb + (size_t)S * D;
  __bf16* Qb = (__bf16*)d_ws;
  __bf16* Kb = Qb + (size_t)S * D;
  __bf16* vT = Kb + (size_t)S * D;

  convert_all<<<3072 + 432, 256, 0, stream>>>(x, xb, Wq, WT);
  qkv_gemm   <<<dim3(S / 128, N3 / 96), 256, 0, stream>>>(xb, WT, bq, Qb, Kb, vT);
  attention  <<<dim3(S / 64, H), 256, 0, stream>>>(Qb, Kb, vT, mask, (float*)d_out);
}